// Round 10
// baseline (191.364 us; speedup 1.0000x reference)
//
#include <hip/hip_runtime.h>
#include <math.h>

#define BB 2
#define SS 2048
#define DM 1024
#define NH 16
#define HD 64

typedef __attribute__((ext_vector_type(8))) __bf16 bf16x8;
typedef __attribute__((ext_vector_type(4))) __bf16 bf16x4;
typedef __attribute__((ext_vector_type(8))) unsigned short u16x8;
typedef __attribute__((ext_vector_type(4))) float f32x4;
typedef unsigned short u16;
typedef unsigned int u32;
typedef __attribute__((address_space(1))) unsigned int u32g;
typedef __attribute__((address_space(3))) unsigned int u32l;

#define CEXP 0.18033688011112042f   // 0.125 * log2(e)

static __device__ __forceinline__ u16 f2bf(float f) {
    __bf16 h = (__bf16)f;
    return __builtin_bit_cast(unsigned short, h);
}

// async global->LDS, 16B/lane; lds base wave-uniform, lane i lands at base + i*16B
static __device__ __forceinline__ void gld16(const u16* g, u16* l) {
    __builtin_amdgcn_global_load_lds((const u32g*)g, (u32l*)l, 16, 0, 0);
}

// ---------------- fused fp32 -> bf16 cast for x + 4 weights ----------------
__global__ __launch_bounds__(256)
void cast_all(const float* __restrict__ x,
              const float* __restrict__ wq, const float* __restrict__ wk,
              const float* __restrict__ wv, const float* __restrict__ wo,
              u16* __restrict__ xb, u16* __restrict__ wqb, u16* __restrict__ wkb,
              u16* __restrict__ wvb, u16* __restrict__ wob)
{
    const int N4X = (BB * SS * DM) / 4;   // 1048576
    const int N4W = (DM * DM) / 4;        // 262144
    int i = blockIdx.x * 256 + threadIdx.x;
    const float* src; u16* dst; int off;
    if (i < N4X) { src = x; dst = xb; off = i; }
    else {
        int i2 = i - N4X;
        int w = i2 >> 18;
        off = i2 & (N4W - 1);
        switch (w) {
            case 0:  src = wq; dst = wqb; break;
            case 1:  src = wk; dst = wkb; break;
            case 2:  src = wv; dst = wvb; break;
            default: src = wo; dst = wob; break;
        }
    }
    float4 v = ((const float4*)src)[off];
    ushort4 o;
    o.x = f2bf(v.x); o.y = f2bf(v.y); o.z = f2bf(v.z); o.w = f2bf(v.w);
    ((ushort4*)dst)[off] = o;
}

// ---------------- QKV projection: BK=64 swizzled gld16; fp32 RoPE; transposed epilogue ------
// z==0/1 -> Q/K in [b,h,s,d]; z==2 -> V written TRANSPOSED [b,h,d,s] for attn gld16 staging.
__global__ __launch_bounds__(256, 3)
void qkv_gemm(const u16* __restrict__ X,
              const u16* __restrict__ Wq, const u16* __restrict__ Wk,
              const u16* __restrict__ Wv,
              const int* __restrict__ tp, const float* __restrict__ cosp,
              const float* __restrict__ sinp, const int* __restrict__ use_rope,
              u16* __restrict__ Q, u16* __restrict__ K, u16* __restrict__ V)
{
    const u16* W; u16* dst;
    if (blockIdx.z == 0)      { W = Wq; dst = Q; }
    else if (blockIdx.z == 1) { W = Wk; dst = K; }
    else                      { W = Wv; dst = V; }

    __shared__ u16 SH[4 * 64 * 68];   // 34816 B: {As,Bs} during k-loop; Ts after
    u16* As = SH;                     // 128 x 64
    u16* Bs = SH + 8192;              // 128 x 64
    const int t  = threadIdx.x;
    const int wv = t >> 6, L = t & 63, ln = L & 15, qd = L >> 4;
    const int i0 = blockIdx.y * 128, j0 = blockIdx.x * 128;
    const int wm = (wv >> 1) * 64, wn = (wv & 1) * 64;
    const int srow = L >> 3;
    const int scg  = ((L & 7) ^ (L >> 3)) * 8;

    f32x4 acc[4][4];
    #pragma unroll
    for (int a = 0; a < 4; ++a)
        #pragma unroll
        for (int b = 0; b < 4; ++b)
            #pragma unroll
            for (int e = 0; e < 4; ++e) acc[a][b][e] = 0.f;

    for (int k0 = 0; k0 < DM; k0 += 64) {
        __syncthreads();
        #pragma unroll
        for (int g = 0; g < 4; ++g) {
            int rb = wv * 32 + g * 8;
            gld16(X + (size_t)(i0 + rb + srow) * DM + k0 + scg, &As[rb * 64]);
            gld16(W + (size_t)(j0 + rb + srow) * DM + k0 + scg, &Bs[rb * 64]);
        }
        __syncthreads();
        bf16x8 a[4][2], b[4][2];
        #pragma unroll
        for (int mi = 0; mi < 4; ++mi)
            #pragma unroll
            for (int kd = 0; kd < 2; ++kd)
                a[mi][kd] = *(const bf16x8*)&As[(wm + mi * 16 + ln) * 64 + (((kd * 4 + qd) ^ (ln & 7)) * 8)];
        #pragma unroll
        for (int ni = 0; ni < 4; ++ni)
            #pragma unroll
            for (int kd = 0; kd < 2; ++kd)
                b[ni][kd] = *(const bf16x8*)&Bs[(wn + ni * 16 + ln) * 64 + (((kd * 4 + qd) ^ (ln & 7)) * 8)];
        #pragma unroll
        for (int kd = 0; kd < 2; ++kd)
            #pragma unroll
            for (int mi = 0; mi < 4; ++mi)
                #pragma unroll
                for (int ni = 0; ni < 4; ++ni)
                    acc[mi][ni] = __builtin_amdgcn_mfma_f32_16x16x32_bf16(a[mi][kd], b[ni][kd], acc[mi][ni], 0, 0, 0);
    }

    // ---- RoPE in fp32 on accumulators (lane pairs hold adjacent d) ----
    const int rope_on = (blockIdx.z < 2) ? use_rope[0] : 0;
    if (rope_on) {
        #pragma unroll
        for (int mi = 0; mi < 4; ++mi)
            #pragma unroll
            for (int r = 0; r < 4; ++r) {
                int gi = i0 + wm + mi * 16 + qd * 4 + r;
                int s = gi & 2047;
                int pos = tp[s];
                #pragma unroll
                for (int ni = 0; ni < 4; ++ni) {
                    int d = wn + ni * 16 + ln;
                    int dh = d & 63;
                    float c  = cosp[pos * 32 + (dh >> 1)];
                    float sn = sinp[pos * 32 + (dh >> 1)];
                    float v = acc[mi][ni][r];
                    float pv = __shfl_xor(v, 1);
                    acc[mi][ni][r] = (dh & 1) ? (v * c + pv * sn) : (v * c - pv * sn);
                }
            }
    }

    // ---- epilogue: per-wave LDS transpose ----
    __syncthreads();
    u16* Ts = SH + wv * (64 * 68);    // 64 rows (s) x 64 cols (d), stride 68
    #pragma unroll
    for (int mi = 0; mi < 4; ++mi)
        #pragma unroll
        for (int ni = 0; ni < 4; ++ni)
            #pragma unroll
            for (int r = 0; r < 4; ++r)
                Ts[(mi * 16 + qd * 4 + r) * 68 + ni * 16 + ln] = f2bf(acc[mi][ni][r]);

    const int h  = blockIdx.x * 2 + (wv & 1);
    const int sb = i0 + wm;
    const int b_ = sb >> 11, s0 = sb & 2047;
    if (blockIdx.z < 2) {
        // Q/K: [b,h,s,d] coalesced u16x8 rows
        const int lrow = L >> 3, lcol = (L & 7) * 8;
        #pragma unroll
        for (int r2 = 0; r2 < 8; ++r2) {
            int row = lrow + r2 * 8;
            u16x8 val = *(const u16x8*)&Ts[row * 68 + lcol];
            *(u16x8*)&dst[(((size_t)(b_ * NH + h)) * SS + s0 + row) * HD + lcol] = val;
        }
    } else {
        // V: transposed [b,h,d,s] (8 s per lane along the row)
        const int sch = (L & 7) * 8;      // s-chunk within the 64-row tile
        const int dr0 = L >> 3;           // d-row base
        #pragma unroll
        for (int r2 = 0; r2 < 8; ++r2) {
            int d = dr0 + r2 * 8;
            u16x8 val;
            #pragma unroll
            for (int u = 0; u < 8; ++u) val[u] = Ts[(sch + u) * 68 + d];
            *(u16x8*)&dst[(((size_t)(b_ * NH + h)) * HD + d) * SS + s0 + sch] = val;
        }
    }
}

// ---------------- output projection, 128x64 tile, fp32 transposed epilogue ----------------
__global__ __launch_bounds__(256, 2)
void out_gemm(const u16* __restrict__ X, const u16* __restrict__ W,
              float* __restrict__ dst)
{
    __shared__ char SHB[36864];       // {As 16K, Bs 8K} k-loop; Ts 36K epilogue
    u16* As = (u16*)SHB;              // 128 x 64
    u16* Bs = (u16*)SHB + 8192;       // 64 x 64
    const int t  = threadIdx.x;
    const int wv = t >> 6, L = t & 63, ln = L & 15, qd = L >> 4;
    const int i0 = blockIdx.y * 128, j0 = blockIdx.x * 64;
    const int wm = (wv >> 1) * 64, wn = (wv & 1) * 32;
    const int srow = L >> 3;
    const int scg  = ((L & 7) ^ (L >> 3)) * 8;

    f32x4 acc[4][2];
    #pragma unroll
    for (int mi = 0; mi < 4; ++mi)
        #pragma unroll
        for (int ni = 0; ni < 2; ++ni)
            #pragma unroll
            for (int e = 0; e < 4; ++e) acc[mi][ni][e] = 0.f;

    for (int k0 = 0; k0 < DM; k0 += 64) {
        __syncthreads();
        #pragma unroll
        for (int g = 0; g < 4; ++g) {
            int rb = wv * 32 + g * 8;
            gld16(X + (size_t)(i0 + rb + srow) * DM + k0 + scg, &As[rb * 64]);
        }
        #pragma unroll
        for (int g = 0; g < 2; ++g) {
            int rb = wv * 16 + g * 8;
            gld16(W + (size_t)(j0 + rb + srow) * DM + k0 + scg, &Bs[rb * 64]);
        }
        __syncthreads();
        bf16x8 a[4][2], b[2][2];
        #pragma unroll
        for (int mi = 0; mi < 4; ++mi)
            #pragma unroll
            for (int kd = 0; kd < 2; ++kd)
                a[mi][kd] = *(const bf16x8*)&As[(wm + mi * 16 + ln) * 64 + (((kd * 4 + qd) ^ (ln & 7)) * 8)];
        #pragma unroll
        for (int ni = 0; ni < 2; ++ni)
            #pragma unroll
            for (int kd = 0; kd < 2; ++kd)
                b[ni][kd] = *(const bf16x8*)&Bs[(wn + ni * 16 + ln) * 64 + (((kd * 4 + qd) ^ (ln & 7)) * 8)];
        #pragma unroll
        for (int kd = 0; kd < 2; ++kd)
            #pragma unroll
            for (int mi = 0; mi < 4; ++mi)
                #pragma unroll
                for (int ni = 0; ni < 2; ++ni)
                    acc[mi][ni] = __builtin_amdgcn_mfma_f32_16x16x32_bf16(a[mi][kd], b[ni][kd], acc[mi][ni], 0, 0, 0);
    }

    __syncthreads();
    float* Ts = (float*)SHB + wv * (64 * 36);   // 64 rows x 32 cols, stride 36
    #pragma unroll
    for (int mi = 0; mi < 4; ++mi)
        #pragma unroll
        for (int ni = 0; ni < 2; ++ni)
            #pragma unroll
            for (int r = 0; r < 4; ++r)
                Ts[(mi * 16 + qd * 4 + r) * 36 + ni * 16 + ln] = acc[mi][ni][r];

    const int lrow = L >> 3, lch = L & 7;
    #pragma unroll
    for (int r2 = 0; r2 < 8; ++r2) {
        int row = lrow + r2 * 8;
        float4 v = *(const float4*)&Ts[row * 36 + lch * 4];
        *(float4*)&dst[(size_t)(i0 + wm + row) * DM + j0 + wn + lch * 4] = v;
    }
}

// ---------------- MFMA flash attention: quarter-tile blocks, 4 blocks/CU ----------------
// Block = 256 thr = 4 waves. Waves 0-1: rows [h*32, h*32+32) of q-tile p;
// waves 2-3: same rows of q-tile 31-p. Every block does exactly 66 wave-iters.
static __device__ __forceinline__ void group_step(
    const u16* KsB, const bf16x8 qf[2], u16* psw,
    bool diag, int rowg, int j0, int ln, int qd,
    float& m, float& l, f32x4* o, bf16x8& pf0, bf16x8& pf1)
{
    const int pm = 2 * (ln & 7);     // even XOR mask over 8B granules
    f32x4 s[4];
    #pragma unroll
    for (int mt = 0; mt < 4; ++mt) {
        bf16x8 a0 = *(const bf16x8*)&KsB[(mt * 16 + ln) * 64 + ((qd ^ (ln & 7)) * 8)];
        bf16x8 a1 = *(const bf16x8*)&KsB[(mt * 16 + ln) * 64 + (((4 + qd) ^ (ln & 7)) * 8)];
        #pragma unroll
        for (int e = 0; e < 4; ++e) s[mt][e] = 0.f;
        s[mt] = __builtin_amdgcn_mfma_f32_16x16x32_bf16(a0, qf[0], s[mt], 0, 0, 0);
        s[mt] = __builtin_amdgcn_mfma_f32_16x16x32_bf16(a1, qf[1], s[mt], 0, 0, 0);
    }
    if (diag) {
        #pragma unroll
        for (int mt = 0; mt < 4; ++mt)
            #pragma unroll
            for (int r = 0; r < 4; ++r)
                if (j0 + mt * 16 + qd * 4 + r > rowg) s[mt][r] = -3.0e38f;
    }
    float rm = s[0][0];
    #pragma unroll
    for (int mt = 0; mt < 4; ++mt)
        #pragma unroll
        for (int r = 0; r < 4; ++r) rm = fmaxf(rm, s[mt][r]);
    rm = fmaxf(rm, __shfl_xor(rm, 16));
    rm = fmaxf(rm, __shfl_xor(rm, 32));
    float nm = fmaxf(m, rm);
    float alpha = exp2f((m - nm) * CEXP);
    float nmc = nm * CEXP;
    float rs = 0.f;
    #pragma unroll
    for (int mt = 0; mt < 4; ++mt) {
        bf16x4 pk;
        #pragma unroll
        for (int r = 0; r < 4; ++r) {
            float pv = exp2f(fmaf(s[mt][r], CEXP, -nmc));
            rs += pv;
            pk[r] = (__bf16)pv;
        }
        *(bf16x4*)(psw + ln * 64 + ((mt * 4 + qd) ^ pm) * 4) = pk;
    }
    rs += __shfl_xor(rs, 16);
    rs += __shfl_xor(rs, 32);
    l = l * alpha + rs;
    m = nm;
    // O^T layout: col = q = own lane -> in-lane rescale, no broadcast
    #pragma unroll
    for (int ni = 0; ni < 4; ++ni)
        #pragma unroll
        for (int r = 0; r < 4; ++r) o[ni][r] *= alpha;
    pf0 = *(const bf16x8*)(psw + ln * 64 + ((qd * 2) ^ pm) * 4);
    pf1 = *(const bf16x8*)(psw + ln * 64 + ((8 + qd * 2) ^ pm) * 4);
}

__global__ __launch_bounds__(256, 8)
void attn_kernel(const u16* __restrict__ Q, const u16* __restrict__ K,
                 const u16* __restrict__ V, u16* __restrict__ Y)
{
    __shared__ u16 Ks[2][64 * 64];     // [key][d], gld16 source-swizzled, double-buffered
    __shared__ u16 Vt[2][64 * 64];     // [d][key] from global V^T, gld16, double-buffered
    __shared__ u16 Ps[4][16 * 64];     // per-wave P round-trip, granule-swizzled

    const int t  = threadIdx.x;
    const int wv = t >> 6, L = t & 63, ln = L & 15, qd = L >> 4;
    const int wsub = wv & 1, grp = wv >> 1;
    const int bh = blockIdx.x, p = blockIdx.y, hh = blockIdx.z;
    const int qb = (grp ? (31 - p) : p) * 64 + hh * 32;
    const u16* Qp = Q + (size_t)bh * SS * HD;
    const u16* Kp = K + (size_t)bh * SS * HD;
    const u16* Vp = V + (size_t)bh * HD * SS;   // transposed [d][s]
    const int srow = L >> 3;
    const int scg  = ((L & 7) ^ (L >> 3)) * 8;

    const int ntile   = 32 - p;
    const int myTiles = grp ? ntile : (p + 1);

    bf16x8 qf[2];
    {
        const u16* rq = Qp + (size_t)(qb + wsub * 16 + ln) * HD;
        qf[0] = *(const bf16x8*)(rq + qd * 8);
        qf[1] = *(const bf16x8*)(rq + 32 + qd * 8);
    }

    f32x4 o[4];
    #pragma unroll
    for (int ni = 0; ni < 4; ++ni)
        #pragma unroll
        for (int e = 0; e < 4; ++e) o[ni][e] = 0.f;
    float m = -3.0e38f, l = 0.f;

    // ---- prologue: stage tile 0 (K: 4 waves x 16 rows; V^T: 4 waves x 16 d-rows) ----
    gld16(Kp + (size_t)(wv * 16 +     srow) * HD + scg, &Ks[0][(wv * 16    ) * 64]);
    gld16(Kp + (size_t)(wv * 16 + 8 + srow) * HD + scg, &Ks[0][(wv * 16 + 8) * 64]);
    gld16(Vp + (size_t)(wv * 16 +     srow) * SS + scg, &Vt[0][(wv * 16    ) * 64]);
    gld16(Vp + (size_t)(wv * 16 + 8 + srow) * SS + scg, &Vt[0][(wv * 16 + 8) * 64]);
    __syncthreads();

    for (int tix = 0; tix < ntile; ++tix) {
        const int j0 = tix * 64;
        const int buf = tix & 1;
        const bool more = (tix + 1 < ntile);

        // ---- prefetch tile t+1 async into buf^1 ----
        if (more) {
            const int j1 = j0 + 64;
            gld16(Kp + (size_t)(j1 + wv * 16 +     srow) * HD + scg, &Ks[buf ^ 1][(wv * 16    ) * 64]);
            gld16(Kp + (size_t)(j1 + wv * 16 + 8 + srow) * HD + scg, &Ks[buf ^ 1][(wv * 16 + 8) * 64]);
            gld16(Vp + (size_t)(wv * 16 +     srow) * SS + j1 + scg, &Vt[buf ^ 1][(wv * 16    ) * 64]);
            gld16(Vp + (size_t)(wv * 16 + 8 + srow) * SS + j1 + scg, &Vt[buf ^ 1][(wv * 16 + 8) * 64]);
        }

        if (tix < myTiles) {
            bf16x8 pf0, pf1;
            group_step(Ks[buf], qf, &Ps[wv][0], tix == myTiles - 1,
                       qb + wsub * 16 + ln, j0, ln, qd, m, l, o, pf0, pf1);
            #pragma unroll
            for (int kc = 0; kc < 2; ++kc)
                #pragma unroll
                for (int ni = 0; ni < 4; ++ni) {
                    bf16x8 vf = *(const bf16x8*)&Vt[buf][(ni * 16 + ln) * 64 + (((kc * 4 + qd) ^ (ln & 7)) * 8)];
                    // O^T = V^T * P : A = V^T frag, B = P frag
                    o[ni] = __builtin_amdgcn_mfma_f32_16x16x32_bf16(vf, kc ? pf1 : pf0, o[ni], 0, 0, 0);
                }
        }
        __syncthreads();
    }

    // ---- epilogue: normalize in-lane, write Y bf16 (b, s, d_model), 8B runs ----
    const int b = bh >> 4, h = bh & 15;
    const float inv = 1.f / l;
    const int sq = qb + wsub * 16 + ln;
    #pragma unroll
    for (int ni = 0; ni < 4; ++ni) {
        bf16x4 pk;
        #pragma unroll
        for (int r = 0; r < 4; ++r) pk[r] = (__bf16)(o[ni][r] * inv);
        *(bf16x4*)&Y[((size_t)(b * SS + sq)) * DM + h * HD + ni * 16 + qd * 4] = pk;
    }
}

extern "C" void kernel_launch(void* const* d_in, const int* in_sizes, int n_in,
                              void* d_out, int out_size, void* d_ws, size_t ws_size,
                              hipStream_t stream)
{
    const float* x        = (const float*)d_in[0];
    const int*   tp       = (const int*)d_in[1];
    const int*   use_rope = (const int*)d_in[2];
    const float* Wq       = (const float*)d_in[3];
    const float* Wk       = (const float*)d_in[4];
    const float* Wv       = (const float*)d_in[5];
    const float* Wo       = (const float*)d_in[6];
    const float* cosp     = (const float*)d_in[7];
    const float* sinp     = (const float*)d_in[8];
    float* out = (float*)d_out;

    char* ws = (char*)d_ws;
    const size_t MB = 1 << 20;
    u16* xb  = (u16*)(ws);
    u16* Wqb = (u16*)(ws + 8 * MB);
    u16* Wkb = (u16*)(ws + 10 * MB);
    u16* Wvb = (u16*)(ws + 12 * MB);
    u16* Wob = (u16*)(ws + 14 * MB);
    u16* Qb  = (u16*)(ws + 16 * MB);
    u16* Kb  = (u16*)(ws + 24 * MB);
    u16* Vb  = (u16*)(ws + 32 * MB);
    u16* Yb  = (u16*)(ws + 40 * MB);

    cast_all<<<8192, 256, 0, stream>>>(x, Wq, Wk, Wv, Wo, xb, Wqb, Wkb, Wvb, Wob);
    qkv_gemm<<<dim3(DM / 128, BB * SS / 128, 3), 256, 0, stream>>>(
        xb, Wqb, Wkb, Wvb, tp, cosp, sinp, use_rope, Qb, Kb, Vb);
    attn_kernel<<<dim3(BB * NH, 16, 2), 256, 0, stream>>>(Qb, Kb, Vb, Yb);
    out_gemm<<<dim3(DM / 64, BB * SS / 128), 256, 0, stream>>>(Yb, Wob, out);
}

// Round 11
// 181.559 us; speedup vs baseline: 1.0540x; 1.0540x over previous
//
#include <hip/hip_runtime.h>
#include <math.h>

#define BB 2
#define SS 2048
#define DM 1024
#define NH 16
#define HD 64

typedef __attribute__((ext_vector_type(8))) __bf16 bf16x8;
typedef __attribute__((ext_vector_type(4))) __bf16 bf16x4;
typedef __attribute__((ext_vector_type(8))) unsigned short u16x8;
typedef __attribute__((ext_vector_type(4))) float f32x4;
typedef unsigned short u16;
typedef unsigned int u32;
typedef __attribute__((address_space(1))) unsigned int u32g;
typedef __attribute__((address_space(3))) unsigned int u32l;

#define CEXP 0.18033688011112042f   // 0.125 * log2(e)

static __device__ __forceinline__ u16 f2bf(float f) {
    __bf16 h = (__bf16)f;
    return __builtin_bit_cast(unsigned short, h);
}

// async global->LDS, 16B/lane; lds base wave-uniform, lane i lands at base + i*16B
static __device__ __forceinline__ void gld16(const u16* g, u16* l) {
    __builtin_amdgcn_global_load_lds((const u32g*)g, (u32l*)l, 16, 0, 0);
}

// ---------------- fused fp32 -> bf16 cast for x + 4 weights ----------------
__global__ __launch_bounds__(256)
void cast_all(const float* __restrict__ x,
              const float* __restrict__ wq, const float* __restrict__ wk,
              const float* __restrict__ wv, const float* __restrict__ wo,
              u16* __restrict__ xb, u16* __restrict__ wqb, u16* __restrict__ wkb,
              u16* __restrict__ wvb, u16* __restrict__ wob)
{
    const int N4X = (BB * SS * DM) / 4;   // 1048576
    const int N4W = (DM * DM) / 4;        // 262144
    int i = blockIdx.x * 256 + threadIdx.x;
    const float* src; u16* dst; int off;
    if (i < N4X) { src = x; dst = xb; off = i; }
    else {
        int i2 = i - N4X;
        int w = i2 >> 18;
        off = i2 & (N4W - 1);
        switch (w) {
            case 0:  src = wq; dst = wqb; break;
            case 1:  src = wk; dst = wkb; break;
            case 2:  src = wv; dst = wvb; break;
            default: src = wo; dst = wob; break;
        }
    }
    float4 v = ((const float4*)src)[off];
    ushort4 o;
    o.x = f2bf(v.x); o.y = f2bf(v.y); o.z = f2bf(v.z); o.w = f2bf(v.w);
    ((ushort4*)dst)[off] = o;
}

// ---------------- QKV projection: BK=64 swizzled gld16; fp32 RoPE; transposed epilogue ------
// z==0/1 -> Q/K in [b,h,s,d]; z==2 -> V written TRANSPOSED [b,h,d,s] for attn gld16 staging.
__global__ __launch_bounds__(256, 3)
void qkv_gemm(const u16* __restrict__ X,
              const u16* __restrict__ Wq, const u16* __restrict__ Wk,
              const u16* __restrict__ Wv,
              const int* __restrict__ tp, const float* __restrict__ cosp,
              const float* __restrict__ sinp, const int* __restrict__ use_rope,
              u16* __restrict__ Q, u16* __restrict__ K, u16* __restrict__ V)
{
    const u16* W; u16* dst;
    if (blockIdx.z == 0)      { W = Wq; dst = Q; }
    else if (blockIdx.z == 1) { W = Wk; dst = K; }
    else                      { W = Wv; dst = V; }

    __shared__ u16 SH[4 * 64 * 68];   // 34816 B: {As,Bs} during k-loop; Ts after
    u16* As = SH;                     // 128 x 64
    u16* Bs = SH + 8192;              // 128 x 64
    const int t  = threadIdx.x;
    const int wv = t >> 6, L = t & 63, ln = L & 15, qd = L >> 4;
    const int i0 = blockIdx.y * 128, j0 = blockIdx.x * 128;
    const int wm = (wv >> 1) * 64, wn = (wv & 1) * 64;
    const int srow = L >> 3;
    const int scg  = ((L & 7) ^ (L >> 3)) * 8;

    f32x4 acc[4][4];
    #pragma unroll
    for (int a = 0; a < 4; ++a)
        #pragma unroll
        for (int b = 0; b < 4; ++b)
            #pragma unroll
            for (int e = 0; e < 4; ++e) acc[a][b][e] = 0.f;

    for (int k0 = 0; k0 < DM; k0 += 64) {
        __syncthreads();
        #pragma unroll
        for (int g = 0; g < 4; ++g) {
            int rb = wv * 32 + g * 8;
            gld16(X + (size_t)(i0 + rb + srow) * DM + k0 + scg, &As[rb * 64]);
            gld16(W + (size_t)(j0 + rb + srow) * DM + k0 + scg, &Bs[rb * 64]);
        }
        __syncthreads();
        bf16x8 a[4][2], b[4][2];
        #pragma unroll
        for (int mi = 0; mi < 4; ++mi)
            #pragma unroll
            for (int kd = 0; kd < 2; ++kd)
                a[mi][kd] = *(const bf16x8*)&As[(wm + mi * 16 + ln) * 64 + (((kd * 4 + qd) ^ (ln & 7)) * 8)];
        #pragma unroll
        for (int ni = 0; ni < 4; ++ni)
            #pragma unroll
            for (int kd = 0; kd < 2; ++kd)
                b[ni][kd] = *(const bf16x8*)&Bs[(wn + ni * 16 + ln) * 64 + (((kd * 4 + qd) ^ (ln & 7)) * 8)];
        #pragma unroll
        for (int kd = 0; kd < 2; ++kd)
            #pragma unroll
            for (int mi = 0; mi < 4; ++mi)
                #pragma unroll
                for (int ni = 0; ni < 4; ++ni)
                    acc[mi][ni] = __builtin_amdgcn_mfma_f32_16x16x32_bf16(a[mi][kd], b[ni][kd], acc[mi][ni], 0, 0, 0);
    }

    // ---- RoPE in fp32 on accumulators (lane pairs hold adjacent d) ----
    const int rope_on = (blockIdx.z < 2) ? use_rope[0] : 0;
    if (rope_on) {
        #pragma unroll
        for (int mi = 0; mi < 4; ++mi)
            #pragma unroll
            for (int r = 0; r < 4; ++r) {
                int gi = i0 + wm + mi * 16 + qd * 4 + r;
                int s = gi & 2047;
                int pos = tp[s];
                #pragma unroll
                for (int ni = 0; ni < 4; ++ni) {
                    int d = wn + ni * 16 + ln;
                    int dh = d & 63;
                    float c  = cosp[pos * 32 + (dh >> 1)];
                    float sn = sinp[pos * 32 + (dh >> 1)];
                    float v = acc[mi][ni][r];
                    float pv = __shfl_xor(v, 1);
                    acc[mi][ni][r] = (dh & 1) ? (v * c + pv * sn) : (v * c - pv * sn);
                }
            }
    }

    // ---- epilogue: per-wave LDS transpose ----
    __syncthreads();
    u16* Ts = SH + wv * (64 * 68);    // 64 rows (s) x 64 cols (d), stride 68
    #pragma unroll
    for (int mi = 0; mi < 4; ++mi)
        #pragma unroll
        for (int ni = 0; ni < 4; ++ni)
            #pragma unroll
            for (int r = 0; r < 4; ++r)
                Ts[(mi * 16 + qd * 4 + r) * 68 + ni * 16 + ln] = f2bf(acc[mi][ni][r]);

    const int h  = blockIdx.x * 2 + (wv & 1);
    const int sb = i0 + wm;
    const int b_ = sb >> 11, s0 = sb & 2047;
    if (blockIdx.z < 2) {
        // Q/K: [b,h,s,d] coalesced u16x8 rows
        const int lrow = L >> 3, lcol = (L & 7) * 8;
        #pragma unroll
        for (int r2 = 0; r2 < 8; ++r2) {
            int row = lrow + r2 * 8;
            u16x8 val = *(const u16x8*)&Ts[row * 68 + lcol];
            *(u16x8*)&dst[(((size_t)(b_ * NH + h)) * SS + s0 + row) * HD + lcol] = val;
        }
    } else {
        // V: transposed [b,h,d,s] (8 s per lane along the row)
        const int sch = (L & 7) * 8;      // s-chunk within the 64-row tile
        const int dr0 = L >> 3;           // d-row base
        #pragma unroll
        for (int r2 = 0; r2 < 8; ++r2) {
            int d = dr0 + r2 * 8;
            u16x8 val;
            #pragma unroll
            for (int u = 0; u < 8; ++u) val[u] = Ts[(sch + u) * 68 + d];
            *(u16x8*)&dst[(((size_t)(b_ * NH + h)) * HD + d) * SS + s0 + sch] = val;
        }
    }
}

// ---------------- output projection, 128x64 tile, fp32 transposed epilogue ----------------
__global__ __launch_bounds__(256, 2)
void out_gemm(const u16* __restrict__ X, const u16* __restrict__ W,
              float* __restrict__ dst)
{
    __shared__ char SHB[36864];       // {As 16K, Bs 8K} k-loop; Ts 36K epilogue
    u16* As = (u16*)SHB;              // 128 x 64
    u16* Bs = (u16*)SHB + 8192;       // 64 x 64
    const int t  = threadIdx.x;
    const int wv = t >> 6, L = t & 63, ln = L & 15, qd = L >> 4;
    const int i0 = blockIdx.y * 128, j0 = blockIdx.x * 64;
    const int wm = (wv >> 1) * 64, wn = (wv & 1) * 32;
    const int srow = L >> 3;
    const int scg  = ((L & 7) ^ (L >> 3)) * 8;

    f32x4 acc[4][2];
    #pragma unroll
    for (int mi = 0; mi < 4; ++mi)
        #pragma unroll
        for (int ni = 0; ni < 2; ++ni)
            #pragma unroll
            for (int e = 0; e < 4; ++e) acc[mi][ni][e] = 0.f;

    for (int k0 = 0; k0 < DM; k0 += 64) {
        __syncthreads();
        #pragma unroll
        for (int g = 0; g < 4; ++g) {
            int rb = wv * 32 + g * 8;
            gld16(X + (size_t)(i0 + rb + srow) * DM + k0 + scg, &As[rb * 64]);
        }
        #pragma unroll
        for (int g = 0; g < 2; ++g) {
            int rb = wv * 16 + g * 8;
            gld16(W + (size_t)(j0 + rb + srow) * DM + k0 + scg, &Bs[rb * 64]);
        }
        __syncthreads();
        bf16x8 a[4][2], b[2][2];
        #pragma unroll
        for (int mi = 0; mi < 4; ++mi)
            #pragma unroll
            for (int kd = 0; kd < 2; ++kd)
                a[mi][kd] = *(const bf16x8*)&As[(wm + mi * 16 + ln) * 64 + (((kd * 4 + qd) ^ (ln & 7)) * 8)];
        #pragma unroll
        for (int ni = 0; ni < 2; ++ni)
            #pragma unroll
            for (int kd = 0; kd < 2; ++kd)
                b[ni][kd] = *(const bf16x8*)&Bs[(wn + ni * 16 + ln) * 64 + (((kd * 4 + qd) ^ (ln & 7)) * 8)];
        #pragma unroll
        for (int kd = 0; kd < 2; ++kd)
            #pragma unroll
            for (int mi = 0; mi < 4; ++mi)
                #pragma unroll
                for (int ni = 0; ni < 2; ++ni)
                    acc[mi][ni] = __builtin_amdgcn_mfma_f32_16x16x32_bf16(a[mi][kd], b[ni][kd], acc[mi][ni], 0, 0, 0);
    }

    __syncthreads();
    float* Ts = (float*)SHB + wv * (64 * 36);   // 64 rows x 32 cols, stride 36
    #pragma unroll
    for (int mi = 0; mi < 4; ++mi)
        #pragma unroll
        for (int ni = 0; ni < 2; ++ni)
            #pragma unroll
            for (int r = 0; r < 4; ++r)
                Ts[(mi * 16 + qd * 4 + r) * 36 + ni * 16 + ln] = acc[mi][ni][r];

    const int lrow = L >> 3, lch = L & 7;
    #pragma unroll
    for (int r2 = 0; r2 < 8; ++r2) {
        int row = lrow + r2 * 8;
        float4 v = *(const float4*)&Ts[row * 36 + lch * 4];
        *(float4*)&dst[(size_t)(i0 + wm + row) * DM + j0 + wn + lch * 4] = v;
    }
}

// ---------------- MFMA flash attention: wave-specialized (R9) + ones-row l-sum ----------
// Waves 0-3 = q-tile p, waves 4-7 = q-tile 31-p. S^T = mfma(K,Q) puts q in lane;
// O^T = mfma(V^T, P) keeps q in lane. Row-sum l via mfma(ones, P) -> in-lane, no shuffles.
static __device__ __forceinline__ float group_step(
    const u16* KsB, const bf16x8 qf[2], u16* psw,
    bool diag, int rowg, int j0, int ln, int qd,
    float& m, f32x4* o, bf16x8& pf0, bf16x8& pf1)
{
    const int pm = 2 * (ln & 7);     // even XOR mask over 8B granules
    f32x4 s[4];
    #pragma unroll
    for (int mt = 0; mt < 4; ++mt) {
        bf16x8 a0 = *(const bf16x8*)&KsB[(mt * 16 + ln) * 64 + ((qd ^ (ln & 7)) * 8)];
        bf16x8 a1 = *(const bf16x8*)&KsB[(mt * 16 + ln) * 64 + (((4 + qd) ^ (ln & 7)) * 8)];
        #pragma unroll
        for (int e = 0; e < 4; ++e) s[mt][e] = 0.f;
        s[mt] = __builtin_amdgcn_mfma_f32_16x16x32_bf16(a0, qf[0], s[mt], 0, 0, 0);
        s[mt] = __builtin_amdgcn_mfma_f32_16x16x32_bf16(a1, qf[1], s[mt], 0, 0, 0);
    }
    if (diag) {
        #pragma unroll
        for (int mt = 0; mt < 4; ++mt)
            #pragma unroll
            for (int r = 0; r < 4; ++r)
                if (j0 + mt * 16 + qd * 4 + r > rowg) s[mt][r] = -3.0e38f;
    }
    float rm = s[0][0];
    #pragma unroll
    for (int mt = 0; mt < 4; ++mt)
        #pragma unroll
        for (int r = 0; r < 4; ++r) rm = fmaxf(rm, s[mt][r]);
    rm = fmaxf(rm, __shfl_xor(rm, 16));
    rm = fmaxf(rm, __shfl_xor(rm, 32));
    float nm = fmaxf(m, rm);
    float alpha = exp2f((m - nm) * CEXP);
    float nmc = nm * CEXP;
    #pragma unroll
    for (int mt = 0; mt < 4; ++mt) {
        bf16x4 pk;
        #pragma unroll
        for (int r = 0; r < 4; ++r)
            pk[r] = (__bf16)exp2f(fmaf(s[mt][r], CEXP, -nmc));
        *(bf16x4*)(psw + ln * 64 + ((mt * 4 + qd) ^ pm) * 4) = pk;
    }
    m = nm;
    // O^T layout: col = q = own lane -> in-lane rescale, no broadcast
    #pragma unroll
    for (int ni = 0; ni < 4; ++ni)
        #pragma unroll
        for (int r = 0; r < 4; ++r) o[ni][r] *= alpha;
    pf0 = *(const bf16x8*)(psw + ln * 64 + ((qd * 2) ^ pm) * 4);
    pf1 = *(const bf16x8*)(psw + ln * 64 + ((8 + qd * 2) ^ pm) * 4);
    return alpha;
}

__global__ __launch_bounds__(512, 4)
void attn_kernel(const u16* __restrict__ Q, const u16* __restrict__ K,
                 const u16* __restrict__ V, u16* __restrict__ Y)
{
    __shared__ u16 Ks[2][64 * 64];     // [key][d], gld16 source-swizzled, double-buffered
    __shared__ u16 Vt[2][64 * 64];     // [d][key] from global V^T, gld16, double-buffered
    __shared__ u16 Ps[8][16 * 64];     // per-wave P round-trip, granule-swizzled

    const int t  = threadIdx.x;
    const int wv = t >> 6, L = t & 63, ln = L & 15, qd = L >> 4;
    const int wsub = wv & 3, grp = wv >> 2;
    const int bh = blockIdx.x, p = blockIdx.y;
    const int qb = (grp ? (31 - p) : p) * 64;
    const u16* Qp = Q + (size_t)bh * SS * HD;
    const u16* Kp = K + (size_t)bh * SS * HD;
    const u16* Vp = V + (size_t)bh * HD * SS;   // transposed [d][s]
    const int srow = L >> 3;
    const int scg  = ((L & 7) ^ (L >> 3)) * 8;

    const int ntile   = 32 - p;
    const int myTiles = grp ? ntile : (p + 1);

    bf16x8 qf[2];
    {
        const u16* rq = Qp + (size_t)(qb + wsub * 16 + ln) * HD;
        qf[0] = *(const bf16x8*)(rq + qd * 8);
        qf[1] = *(const bf16x8*)(rq + 32 + qd * 8);
    }

    // constant ones A-fragment for the l row-sum MFMA
    bf16x8 ones;
    #pragma unroll
    for (int u = 0; u < 8; ++u) ones[u] = (__bf16)1.0f;

    f32x4 o[4];
    #pragma unroll
    for (int ni = 0; ni < 4; ++ni)
        #pragma unroll
        for (int e = 0; e < 4; ++e) o[ni][e] = 0.f;
    float m = -3.0e38f, l = 0.f;

    // ---- prologue: stage tile 0 (K: 8 waves x 8 rows; V^T: 8 waves x 8 d-rows) ----
    gld16(Kp + (size_t)(wv * 8 + srow) * HD + scg, &Ks[0][(wv * 8) * 64]);
    gld16(Vp + (size_t)(wv * 8 + srow) * SS + scg, &Vt[0][(wv * 8) * 64]);
    __syncthreads();

    for (int tix = 0; tix < ntile; ++tix) {
        const int j0 = tix * 64;
        const int buf = tix & 1;
        const bool more = (tix + 1 < ntile);

        // ---- prefetch tile t+1 async into buf^1 ----
        if (more) {
            const int j1 = j0 + 64;
            gld16(Kp + (size_t)(j1 + wv * 8 + srow) * HD + scg, &Ks[buf ^ 1][(wv * 8) * 64]);
            gld16(Vp + (size_t)(wv * 8 + srow) * SS + j1 + scg, &Vt[buf ^ 1][(wv * 8) * 64]);
        }

        if (tix < myTiles) {
            bf16x8 pf0, pf1;
            float alpha = group_step(Ks[buf], qf, &Ps[wv][0], tix == myTiles - 1,
                                     qb + wsub * 16 + ln, j0, ln, qd, m, o, pf0, pf1);
            f32x4 ls;
            #pragma unroll
            for (int e = 0; e < 4; ++e) ls[e] = 0.f;
            ls = __builtin_amdgcn_mfma_f32_16x16x32_bf16(ones, pf0, ls, 0, 0, 0);
            ls = __builtin_amdgcn_mfma_f32_16x16x32_bf16(ones, pf1, ls, 0, 0, 0);
            #pragma unroll
            for (int kc = 0; kc < 2; ++kc)
                #pragma unroll
                for (int ni = 0; ni < 4; ++ni) {
                    bf16x8 vf = *(const bf16x8*)&Vt[buf][(ni * 16 + ln) * 64 + (((kc * 4 + qd) ^ (ln & 7)) * 8)];
                    // O^T = V^T * P : A = V^T frag, B = P frag
                    o[ni] = __builtin_amdgcn_mfma_f32_16x16x32_bf16(vf, kc ? pf1 : pf0, o[ni], 0, 0, 0);
                }
            l = l * alpha + ls[0];
        }
        __syncthreads();
    }

    // ---- epilogue: normalize in-lane, write Y bf16 (b, s, d_model), 8B runs ----
    const int b = bh >> 4, h = bh & 15;
    const float inv = 1.f / l;
    const int sq = qb + wsub * 16 + ln;
    #pragma unroll
    for (int ni = 0; ni < 4; ++ni) {
        bf16x4 pk;
        #pragma unroll
        for (int r = 0; r < 4; ++r) pk[r] = (__bf16)(o[ni][r] * inv);
        *(bf16x4*)&Y[((size_t)(b * SS + sq)) * DM + h * HD + ni * 16 + qd * 4] = pk;
    }
}

extern "C" void kernel_launch(void* const* d_in, const int* in_sizes, int n_in,
                              void* d_out, int out_size, void* d_ws, size_t ws_size,
                              hipStream_t stream)
{
    const float* x        = (const float*)d_in[0];
    const int*   tp       = (const int*)d_in[1];
    const int*   use_rope = (const int*)d_in[2];
    const float* Wq       = (const float*)d_in[3];
    const float* Wk       = (const float*)d_in[4];
    const float* Wv       = (const float*)d_in[5];
    const float* Wo       = (const float*)d_in[6];
    const float* cosp     = (const float*)d_in[7];
    const float* sinp     = (const float*)d_in[8];
    float* out = (float*)d_out;

    char* ws = (char*)d_ws;
    const size_t MB = 1 << 20;
    u16* xb  = (u16*)(ws);
    u16* Wqb = (u16*)(ws + 8 * MB);
    u16* Wkb = (u16*)(ws + 10 * MB);
    u16* Wvb = (u16*)(ws + 12 * MB);
    u16* Wob = (u16*)(ws + 14 * MB);
    u16* Qb  = (u16*)(ws + 16 * MB);
    u16* Kb  = (u16*)(ws + 24 * MB);
    u16* Vb  = (u16*)(ws + 32 * MB);
    u16* Yb  = (u16*)(ws + 40 * MB);

    cast_all<<<8192, 256, 0, stream>>>(x, Wq, Wk, Wv, Wo, xb, Wqb, Wkb, Wvb, Wob);
    qkv_gemm<<<dim3(DM / 128, BB * SS / 128, 3), 256, 0, stream>>>(
        xb, Wqb, Wkb, Wvb, tp, cosp, sinp, use_rope, Qb, Kb, Vb);
    attn_kernel<<<dim3(BB * NH, 16), 512, 0, stream>>>(Qb, Kb, Vb, Yb);
    out_gemm<<<dim3(DM / 64, BB * SS / 128), 256, 0, stream>>>(Yb, Wob, out);
}